// Round 5
// baseline (430.975 us; speedup 1.0000x reference)
//
#include <hip/hip_runtime.h>
#include <stdint.h>

#define FP8_MAX 448.0f

typedef float floatx16 __attribute__((ext_vector_type(16)));
typedef int   intx4    __attribute__((ext_vector_type(4)));
typedef int   intx8    __attribute__((ext_vector_type(8)));

// counted vmcnt waits (memory clobber: fences plain-C LDS ops across them)
#define WAIT_VMCNT_4() asm volatile("s_waitcnt vmcnt(4)" ::: "memory")
#define WAIT_VMCNT_0() asm volatile("s_waitcnt vmcnt(0)" ::: "memory")

// ---- async global->LDS 16B copy (global_load_lds_dwordx4) ----
// HW writes LDS at wave-uniform base + lane*16 (dest forced linear); the
// GLOBAL source address is per-lane free — swizzle applied on the source.
__device__ __forceinline__ void async_copy16(const void* g, void* s) {
    __builtin_amdgcn_global_load_lds(
        (const __attribute__((address_space(1))) void*)g,
        (__attribute__((address_space(3))) void*)s,
        16, 0, 0);
}

// ---- fused fp8 e4m3 quantization of x (scaled) and w (unscaled) ----
// Grid-stride, 16B/lane coalesced loads, 4B/lane coalesced stores.
// nx4 is an exact multiple of stride, so the x/w branch is wave-uniform.
__global__ void __launch_bounds__(256) quant_fp8_kernel(
    const float* __restrict__ x, const float* __restrict__ w,
    const float* __restrict__ scale,
    uint8_t* __restrict__ qx, uint8_t* __restrict__ qw,
    long nx4, long ntot4)
{
    const float invx = 1.0f / scale[0];
    const long stride = (long)gridDim.x * 256;
    for (long g = (long)blockIdx.x * 256 + threadIdx.x; g < ntot4; g += stride) {
        const float4* src; int* dst; float inv; long idx;
        if (g < nx4) { src = (const float4*)x; dst = (int*)qx; inv = invx; idx = g; }
        else         { src = (const float4*)w; dst = (int*)qw; inv = 1.0f; idx = g - nx4; }
        float4 v = src[idx];
        float a = fminf(fmaxf(v.x * inv, -FP8_MAX), FP8_MAX);
        float b = fminf(fmaxf(v.y * inv, -FP8_MAX), FP8_MAX);
        float c = fminf(fmaxf(v.z * inv, -FP8_MAX), FP8_MAX);
        float d = fminf(fmaxf(v.w * inv, -FP8_MAX), FP8_MAX);
        int pk = 0;
        pk = __builtin_amdgcn_cvt_pk_fp8_f32(a, b, pk, false);  // bytes 0..1
        pk = __builtin_amdgcn_cvt_pk_fp8_f32(c, d, pk, true);   // bytes 2..3
        dst[idx] = pk;
    }
}

// ---- fp8 GEMM via MX-scaled MFMA, 256x256 deep-pipelined (T3+T4+T5) ----
// A: qx [M][K] fp8 row-major, B: qw [N][K] fp8 row-major (B^T, K-contig)
// C[m][n] = sum_k A[m][k]*B[n][k];  out = C*osc + bias[n]
//
// Structure (round-5): BM=BN=256, BK=64; 512 threads = 8 waves (2 x 4);
// per wave a 128x64 sub-tile = 4x2 grid of v_mfma_scale_f32_32x32x64_f8f6f4
// (all e8m0 scales = 0x7F = 2^0 -> bit-exact plain fp8xfp8->f32 at the MX
// rate).  96 KB LDS = 3 buffers x (A 16KB + B 16KB); prefetch depth 2.
//
// K-loop schedule (counted vmcnt — the vmcnt(0) drain of the old 2-barrier
// structure NEVER executes in the main loop; m218: counted-vs-drain was the
// entire 8-phase gain):
//   for t:  s_waitcnt vmcnt(4)   // tile t = oldest 4 loads, issued at t-2
//           s_barrier            // (a) tile t visible to all waves
//                                // (b) all waves done computing t-1 -> the
//                                //     buffer stage(t+2) overwrites is free
//           issue stage(t+2) -> buf[(t+2)%3]     (4 global_load_lds)
//           compute(t) from buf[t%3]  (12 ds_read_b128 + 8 MFMA, compiler-
//                                      scheduled lgkmcnt; setprio(1) around)
// Fragment math identical to the round-3/4 VERIFIED kernel: staging slot
// S -> row S>>2, chunk (S&3)^((S>>3)&3) (coalesced: 4 lanes per contiguous
// 64B row segment); read chunks (h*2)^fsw,(h*2+1)^fsw with fsw=(rl>>1)&3.
__global__ void __launch_bounds__(512, 2) gemm_fp8_kernel(
    const uint8_t* __restrict__ A, const uint8_t* __restrict__ B,
    const float* __restrict__ bias,
    const float* __restrict__ in_scale, const float* __restrict__ w_scale,
    float* __restrict__ C, int M, int N, int K)
{
    __shared__ __align__(16) uint8_t As[3][256 * 64];   // 48 KB
    __shared__ __align__(16) uint8_t Bs[3][256 * 64];   // 48 KB

    const int tid  = threadIdx.x;
    const int lane = tid & 63;
    const int wid  = tid >> 6;       // 0..7
    const int wm   = wid >> 2;       // wave row (0..1) -> 128 rows
    const int wn   = wid & 3;        // wave col (0..3) -> 64 cols
    const int m0   = blockIdx.y * 256;
    const int n0   = blockIdx.x * 256;

    const int rl = lane & 31;        // row/col within the 32-block
    const int h  = lane >> 5;        // k-half (0: k 0..31, 1: k 32..63)

    // staging: slot S (0..1023) -> global row S>>2, chunk (S&3)^((S>>3)&3)
    const int S0 = tid, S1 = tid + 512;
    const int rA0 = S0 >> 2, cA0 = ((S0 & 3) ^ ((S0 >> 3) & 3)) * 16;
    const int rA1 = S1 >> 2, cA1 = ((S1 & 3) ^ ((S1 >> 3) & 3)) * 16;

    const uint8_t* Ab = A + (size_t)m0 * K;
    const uint8_t* Bb = B + (size_t)n0 * K;

    floatx16 acc[4][2];
#pragma unroll
    for (int i = 0; i < 4; ++i)
#pragma unroll
        for (int j = 0; j < 2; ++j)
#pragma unroll
            for (int r = 0; r < 16; ++r) acc[i][j][r] = 0.f;

    // fragment reads: logical chunks h*2 / h*2+1, stored at chunk^fsw
    const int fsw  = (rl >> 1) & 3;
    const int ca   = ((h * 2)     ^ fsw) * 16;
    const int cb   = ((h * 2 + 1) ^ fsw) * 16;
    const int aoff = wm * 8192 + rl * 64;    // + mi*2048, mi 0..3
    const int boff = wn * 4096 + rl * 64;    // + ni*2048, ni 0..1

    const int sOne = 0x7F7F7F7F;  // e8m0 = 127 -> 2^0 = 1.0 in every byte
    const int NS = K >> 6;        // K-tiles (64 for K=4096); NS >= 2 assumed

    auto stage = [&](int tile, int buf) {
        const int kt = tile << 6;
        async_copy16(Ab + (size_t)rA0 * K + kt + cA0, As[buf] + S0 * 16);
        async_copy16(Ab + (size_t)rA1 * K + kt + cA1, As[buf] + S1 * 16);
        async_copy16(Bb + (size_t)rA0 * K + kt + cA0, Bs[buf] + S0 * 16);
        async_copy16(Bb + (size_t)rA1 * K + kt + cA1, Bs[buf] + S1 * 16);
    };

    // prologue: tiles 0 and 1 in flight (8 outstanding vmem / thread)
    stage(0, 0);
    stage(1, 1);

    int cur = 0, stg = 2;
    for (int t = 0; t < NS; ++t) {
        if (t < NS - 1) { WAIT_VMCNT_4(); }   // tile t (oldest 4) landed
        else            { WAIT_VMCNT_0(); }
        __builtin_amdgcn_s_barrier();
        __builtin_amdgcn_sched_barrier(0);

        if (t + 2 < NS) {
            stage(t + 2, stg);
            stg = (stg == 2) ? 0 : stg + 1;
        }

        const uint8_t* as = As[cur];
        const uint8_t* bs = Bs[cur];

        intx8 bv[2];
#pragma unroll
        for (int ni = 0; ni < 2; ++ni) {
            intx4 lo = *(const intx4*)(bs + boff + ni * 2048 + ca);
            intx4 hi = *(const intx4*)(bs + boff + ni * 2048 + cb);
            bv[ni] = (intx8){lo[0], lo[1], lo[2], lo[3],
                             hi[0], hi[1], hi[2], hi[3]};
        }

        __builtin_amdgcn_s_setprio(1);
#pragma unroll
        for (int mi = 0; mi < 4; ++mi) {
            intx4 lo = *(const intx4*)(as + aoff + mi * 2048 + ca);
            intx4 hi = *(const intx4*)(as + aoff + mi * 2048 + cb);
            intx8 av = (intx8){lo[0], lo[1], lo[2], lo[3],
                               hi[0], hi[1], hi[2], hi[3]};
            acc[mi][0] = __builtin_amdgcn_mfma_scale_f32_32x32x64_f8f6f4(
                av, bv[0], acc[mi][0], 0, 0, 0, sOne, 0, sOne);
            acc[mi][1] = __builtin_amdgcn_mfma_scale_f32_32x32x64_f8f6f4(
                av, bv[1], acc[mi][1], 0, 0, 0, sOne, 0, sOne);
        }
        __builtin_amdgcn_s_setprio(0);

        cur = (cur == 2) ? 0 : cur + 1;
    }

    const float osc = in_scale[0] * w_scale[0];

    // epilogue: 32x32 C/D layout (m74/m101, shape-determined):
    // col = lane&31, row = (reg&3) + 8*(reg>>2) + 4*(lane>>5)
#pragma unroll
    for (int mi = 0; mi < 4; ++mi) {
#pragma unroll
        for (int ni = 0; ni < 2; ++ni) {
            const int gn = n0 + wn * 64 + ni * 32 + rl;
            const float bvv = bias[gn];
#pragma unroll
            for (int r = 0; r < 16; ++r) {
                const int row = (r & 3) + 8 * (r >> 2) + 4 * h;
                const int gm = m0 + wm * 128 + mi * 32 + row;
                C[(size_t)gm * N + gn] = acc[mi][ni][r] * osc + bvv;
            }
        }
    }
}

extern "C" void kernel_launch(void* const* d_in, const int* in_sizes, int n_in,
                              void* d_out, int out_size, void* d_ws, size_t ws_size,
                              hipStream_t stream) {
    const float* x        = (const float*)d_in[0];  // [M][K]
    const float* weight   = (const float*)d_in[1];  // [N][K], fp8-grid values
    const float* w_scale  = (const float*)d_in[2];  // [1]
    const float* bias     = (const float*)d_in[3];  // [N]
    const float* in_scale = (const float*)d_in[4];  // [1]
    float* out = (float*)d_out;

    const int N = in_sizes[3];                 // D_OUT = 4096
    const int K = in_sizes[1] / N;             // D_IN  = 4096
    const int M = in_sizes[0] / K;             // N_TOK = 8192

    uint8_t* qx = (uint8_t*)d_ws;                          // M*K fp8 (32 MB)
    uint8_t* qw = (uint8_t*)d_ws + (size_t)M * K;          // N*K fp8 (16 MB)

    const long nx4   = (long)M * K / 4;        // 8388608, = 16 * 524288
    const long ntot4 = nx4 + (long)N * K / 4;  // + 4194304
    long blks = (ntot4 + 255) / 256; if (blks > 2048) blks = 2048;
    quant_fp8_kernel<<<(int)blks, 256, 0, stream>>>(x, weight, in_scale,
                                                    qx, qw, nx4, ntot4);

    dim3 grid(N / 256, M / 256);  // (16, 32)
    gemm_fp8_kernel<<<grid, 512, 0, stream>>>(qx, qw, bias, in_scale, w_scale,
                                              out, M, N, K);
}

// Round 6
// 411.106 us; speedup vs baseline: 1.0483x; 1.0483x over previous
//
#include <hip/hip_runtime.h>
#include <stdint.h>

#define FP8_MAX 448.0f

typedef float floatx16 __attribute__((ext_vector_type(16)));
typedef int   intx4    __attribute__((ext_vector_type(4)));
typedef int   intx8    __attribute__((ext_vector_type(8)));

// ---- fused fp8 e4m3 quantization of x (scaled) and w (unscaled) into ----
// ---- MFMA-fragment-native layout ----
// Output layout (per matrix, rows R x cols K): the (32-row x 64-k) fragment
// (rblk = m>>5, kstep = k>>6) is one contiguous 2048B block at
//   frag = rblk*(K>>6) + kstep
// and byte (m,k) lives at  frag*2048 + lane*32 + (k&31)  with
//   lane = (m&31) | (((k>>5)&1)<<5)
// -> lane l of a wave holds row (l&31), k-bytes (l>>5)*32..+32: BYTE-
// IDENTICAL to the fragment registers of the verified round-3/4/5 GEMM.
// Reads stay fully coalesced (float4, row-major); writes are 4B into 32B
// segments (8 txns/wave-store vs 4 ideal) — quant has huge BW slack.
__global__ void __launch_bounds__(256) quant_fp8_frag_kernel(
    const float* __restrict__ x, const float* __restrict__ w,
    const float* __restrict__ scale,
    int* __restrict__ qx, int* __restrict__ qw,
    long nx4, long ntot4, int K, int kshift)
{
    const float invx = 1.0f / scale[0];
    const int rowFrags = K >> 6;
    const long stride = (long)gridDim.x * 256;
    for (long g = (long)blockIdx.x * 256 + threadIdx.x; g < ntot4; g += stride) {
        const float4* src; int* dst; float inv; long idx;
        if (g < nx4) { src = (const float4*)x; dst = qx; inv = invx; idx = g; }
        else         { src = (const float4*)w; dst = qw; inv = 1.0f; idx = g - nx4; }
        float4 v = src[idx];
        float a = fminf(fmaxf(v.x * inv, -FP8_MAX), FP8_MAX);
        float b = fminf(fmaxf(v.y * inv, -FP8_MAX), FP8_MAX);
        float c = fminf(fmaxf(v.z * inv, -FP8_MAX), FP8_MAX);
        float d = fminf(fmaxf(v.w * inv, -FP8_MAX), FP8_MAX);
        int pk = 0;
        pk = __builtin_amdgcn_cvt_pk_fp8_f32(a, b, pk, false);  // bytes 0..1
        pk = __builtin_amdgcn_cvt_pk_fp8_f32(c, d, pk, true);   // bytes 2..3
        const long e = idx * 4;                 // element index, k-aligned to 4
        const int  m = (int)(e >> kshift);      // row
        const int  k = (int)(e & (K - 1));      // col
        const int  frag = (m >> 5) * rowFrags + (k >> 6);
        const int  lane = (m & 31) | (((k >> 5) & 1) << 5);
        dst[frag * 512 + lane * 8 + ((k & 31) >> 2)] = pk;
    }
}

// ---- fp8 GEMM via MX-scaled MFMA, NO LDS (flatmm-style) ----
// A: qx fragment-native [M/32][K/64][2048B], B: qw same [N/32][K/64][2048B]
// C[m][n] = sum_k A[m][k]*B[n][k];  out = C*osc + bias[n]
//
// Round-6 structure: LDS-port analysis (rounds 0-5 all pinned at
// 1580-1600 TF, MfmaUtil<=35%) shows HBM->LDS->reg traffic alone matches
// the MX-MFMA rate at 4x2 blocking — the LDS round-trip IS the roof.
// So: no LDS, no barriers. Block = 256 thr = 4 waves sharing the same 128
// A-rows (A-frags served by L1, x4 reuse); wave wid owns 64 N-cols.
// Per wave per K-step: 4 A-frags + 2 B-frags (12 global dwordx4, each pair
// covers one contiguous 2KB frag at lane*32+{0,16}) + 8
// v_mfma_scale_f32_32x32x64_f8f6f4 (unit e8m0 scales = bit-exact plain
// fp8). Register double-buffer (named sets, static indexing) pipelines
// loads one step ahead; vmcnt scheduling left to the compiler.
// Grid (N/256, M/128): blocks with equal x (same 1MB B-panel) land on the
// same XCD under lin%8 round-robin (16 x-values) -> B stays L2-resident.
__global__ void __launch_bounds__(256) gemm_fp8_kernel(
    const uint8_t* __restrict__ A, const uint8_t* __restrict__ B,
    const float* __restrict__ bias,
    const float* __restrict__ in_scale, const float* __restrict__ w_scale,
    float* __restrict__ C, int M, int N, int K)
{
    const int tid  = threadIdx.x;
    const int lane = tid & 63;
    const int wid  = tid >> 6;       // 0..3: wave's 64-col slice
    const int m0   = blockIdx.y * 128;
    const int n0   = blockIdx.x * 256;

    const int rl = lane & 31;        // row/col within the 32-block
    const int h  = lane >> 5;        // k-half

    const int rowFrags = K >> 6;
    const int NS = rowFrags;         // K-steps (frag stride 2048B per step)

    // fragment stream bases (advance 2048B per K-step)
    const uint8_t* pA[4];
    const uint8_t* pB[2];
#pragma unroll
    for (int mi = 0; mi < 4; ++mi)
        pA[mi] = A + ((size_t)((m0 >> 5) + mi) * rowFrags) * 2048 + lane * 32;
#pragma unroll
    for (int ni = 0; ni < 2; ++ni)
        pB[ni] = B + ((size_t)((n0 >> 5) + wid * 2 + ni) * rowFrags) * 2048 + lane * 32;

    floatx16 acc[4][2];
#pragma unroll
    for (int i = 0; i < 4; ++i)
#pragma unroll
        for (int j = 0; j < 2; ++j)
#pragma unroll
            for (int r = 0; r < 16; ++r) acc[i][j][r] = 0.f;

    const int sOne = 0x7F7F7F7F;  // e8m0 = 127 -> 2^0 = 1.0 in every byte

    auto loadA = [&](intx8* dst, int t) {
#pragma unroll
        for (int mi = 0; mi < 4; ++mi) {
            intx4 lo = *(const intx4*)(pA[mi] + (size_t)t * 2048);
            intx4 hi = *(const intx4*)(pA[mi] + (size_t)t * 2048 + 16);
            dst[mi] = (intx8){lo[0], lo[1], lo[2], lo[3],
                              hi[0], hi[1], hi[2], hi[3]};
        }
    };
    auto loadB = [&](intx8* dst, int t) {
#pragma unroll
        for (int ni = 0; ni < 2; ++ni) {
            intx4 lo = *(const intx4*)(pB[ni] + (size_t)t * 2048);
            intx4 hi = *(const intx4*)(pB[ni] + (size_t)t * 2048 + 16);
            dst[ni] = (intx8){lo[0], lo[1], lo[2], lo[3],
                              hi[0], hi[1], hi[2], hi[3]};
        }
    };
    auto mfma8 = [&](intx8* av, intx8* bv) {
        __builtin_amdgcn_s_setprio(1);
#pragma unroll
        for (int mi = 0; mi < 4; ++mi) {
            acc[mi][0] = __builtin_amdgcn_mfma_scale_f32_32x32x64_f8f6f4(
                av[mi], bv[0], acc[mi][0], 0, 0, 0, sOne, 0, sOne);
            acc[mi][1] = __builtin_amdgcn_mfma_scale_f32_32x32x64_f8f6f4(
                av[mi], bv[1], acc[mi][1], 0, 0, 0, sOne, 0, sOne);
        }
        __builtin_amdgcn_s_setprio(0);
    };

    // register double-buffer, depth 1 (named sets -> static indexing, no scratch)
    intx8 a0[4], b0[2], a1[4], b1[2];
    loadA(a0, 0); loadB(b0, 0);
    loadA(a1, 1); loadB(b1, 1);

    int t = 0;
    for (; t + 2 < NS; t += 2) {
        mfma8(a0, b0);                       // step t
        loadA(a0, t + 2); loadB(b0, t + 2);  // prefetch t+2
        mfma8(a1, b1);                       // step t+1
        loadA(a1, t + 3); loadB(b1, t + 3);  // prefetch t+3
    }
    mfma8(a0, b0);
    mfma8(a1, b1);

    const float osc = in_scale[0] * w_scale[0];

    // epilogue: 32x32 C/D layout (m74/m101, shape-determined):
    // col = lane&31, row = (reg&3) + 8*(reg>>2) + 4*(lane>>5)
#pragma unroll
    for (int mi = 0; mi < 4; ++mi) {
#pragma unroll
        for (int ni = 0; ni < 2; ++ni) {
            const int gn = n0 + wid * 64 + ni * 32 + rl;
            const float bvv = bias[gn];
#pragma unroll
            for (int r = 0; r < 16; ++r) {
                const int row = (r & 3) + 8 * (r >> 2) + 4 * h;
                const int gm = m0 + mi * 32 + row;
                C[(size_t)gm * N + gn] = acc[mi][ni][r] * osc + bvv;
            }
        }
    }
}

extern "C" void kernel_launch(void* const* d_in, const int* in_sizes, int n_in,
                              void* d_out, int out_size, void* d_ws, size_t ws_size,
                              hipStream_t stream) {
    const float* x        = (const float*)d_in[0];  // [M][K]
    const float* weight   = (const float*)d_in[1];  // [N][K], fp8-grid values
    const float* w_scale  = (const float*)d_in[2];  // [1]
    const float* bias     = (const float*)d_in[3];  // [N]
    const float* in_scale = (const float*)d_in[4];  // [1]
    float* out = (float*)d_out;

    const int N = in_sizes[3];                 // D_OUT = 4096
    const int K = in_sizes[1] / N;             // D_IN  = 4096
    const int M = in_sizes[0] / K;             // N_TOK = 8192

    int kshift = 0; while ((1 << kshift) < K) ++kshift;   // K = 4096 -> 12

    uint8_t* qx = (uint8_t*)d_ws;                          // M*K fp8 (32 MB)
    uint8_t* qw = (uint8_t*)d_ws + (size_t)M * K;          // N*K fp8 (16 MB)

    const long nx4   = (long)M * K / 4;        // 8388608, = 16 * 524288
    const long ntot4 = nx4 + (long)N * K / 4;  // + 4194304
    long blks = (ntot4 + 255) / 256; if (blks > 2048) blks = 2048;
    quant_fp8_frag_kernel<<<(int)blks, 256, 0, stream>>>(
        x, weight, in_scale, (int*)qx, (int*)qw, nx4, ntot4, K, kshift);

    dim3 grid(N / 256, M / 128);  // (16, 64)
    gemm_fp8_kernel<<<grid, 256, 0, stream>>>(qx, qw, bias, in_scale, w_scale,
                                              out, M, N, K);
}